// Round 1
// baseline (1056.106 us; speedup 1.0000x reference)
//
#include <hip/hip_runtime.h>
#include <stdint.h>

#define TOKENS 8192
#define HIDDEN 1024
#define INTER  2816
#define NEXP   8

typedef float floatx4 __attribute__((ext_vector_type(4)));
typedef __bf16 bf16x8 __attribute__((ext_vector_type(8)));

__device__ __forceinline__ unsigned short f2bf(float f) {
  unsigned int u = __float_as_uint(f);
  u += 0x7fffu + ((u >> 16) & 1u);
  return (unsigned short)(u >> 16);
}

__device__ __forceinline__ void async16(const void* g, void* l) {
  __builtin_amdgcn_global_load_lds(
      (const __attribute__((address_space(1))) void*)g,
      (__attribute__((address_space(3))) void*)l, 16, 0, 0);
}

// ---------------- fp32 -> bf16 conversion (4 tensors, one launch) ----------------
__global__ void cvt_bf16_4(const float* __restrict__ s0, unsigned short* __restrict__ d0, int n0,
                           const float* __restrict__ s1, unsigned short* __restrict__ d1, int n1,
                           const float* __restrict__ s2, unsigned short* __restrict__ d2, int n2,
                           const float* __restrict__ s3, unsigned short* __restrict__ d3, int n3) {
  const float* s; unsigned short* d; int n;
  switch (blockIdx.z) {
    case 0: s = s0; d = d0; n = n0; break;
    case 1: s = s1; d = d1; n = n1; break;
    case 2: s = s2; d = d2; n = n2; break;
    default: s = s3; d = d3; n = n3; break;
  }
  int i = blockIdx.x * blockDim.x + threadIdx.x;
  int stride = gridDim.x * blockDim.x;
  for (; i < n; i += stride) {
    float4 v = ((const float4*)s)[i];
    ushort4 o;
    o.x = f2bf(v.x); o.y = f2bf(v.y); o.z = f2bf(v.z); o.w = f2bf(v.w);
    ((ushort4*)d)[i] = o;
  }
}

// ---------------- routing: logits -> top2 -> softmax ----------------
__global__ void moe_route(const float* __restrict__ hs,
                          const float* __restrict__ wg,
                          int* __restrict__ counts,
                          int* __restrict__ top_idx,
                          float* __restrict__ top_w) {
  const int token = blockIdx.x * 4 + (threadIdx.x >> 6);
  const int lane = threadIdx.x & 63;
  const float* row = hs + (size_t)token * HIDDEN;
  float acc[NEXP];
#pragma unroll
  for (int e = 0; e < NEXP; e++) acc[e] = 0.f;
  for (int j = lane; j < HIDDEN; j += 64) {
    float x = row[j];
#pragma unroll
    for (int e = 0; e < NEXP; e++) acc[e] += x * wg[e * HIDDEN + j];
  }
#pragma unroll
  for (int e = 0; e < NEXP; e++) {
    float v = acc[e];
    for (int off = 32; off > 0; off >>= 1) v += __shfl_down(v, off);
    acc[e] = v;
  }
  if (lane == 0) {
    int i0 = 0; float v0 = acc[0];
#pragma unroll
    for (int e = 1; e < NEXP; e++) if (acc[e] > v0) { v0 = acc[e]; i0 = e; }
    int i1 = -1; float v1 = -3.0e38f;
#pragma unroll
    for (int e = 0; e < NEXP; e++) if (e != i0 && acc[e] > v1) { v1 = acc[e]; i1 = e; }
    float e1 = __expf(v1 - v0);
    float s = 1.f + e1;
    top_idx[token * 2 + 0] = i0;
    top_idx[token * 2 + 1] = i1;
    top_w[token * 2 + 0] = 1.f / s;
    top_w[token * 2 + 1] = e1 / s;
    atomicAdd(&counts[i0], 1);
    atomicAdd(&counts[i1], 1);
  }
}

__global__ void moe_scan(const int* __restrict__ counts,
                         int* __restrict__ offsets, int* __restrict__ cursor) {
  if (threadIdx.x == 0) {
    int s = 0;
    for (int e = 0; e < NEXP; e++) { offsets[e] = s; cursor[e] = s; s += counts[e]; }
  }
}

__global__ void moe_assign(const int* __restrict__ top_idx,
                           const float* __restrict__ top_w,
                           int* __restrict__ cursor,
                           int* __restrict__ token_of,
                           float* __restrict__ wgt_of,
                           int* __restrict__ slot_of) {
  const int t = blockIdx.x * 256 + threadIdx.x;
#pragma unroll
  for (int k = 0; k < 2; k++) {
    int e = top_idx[t * 2 + k];
    int pos = atomicAdd(&cursor[e], 1);
    token_of[pos] = t;
    wgt_of[pos] = top_w[t * 2 + k];
    slot_of[t * 2 + k] = pos;
  }
}

// LDS layout: per 16-row block (1024 B), element (row, seg[16B]) lives at
//   64*row + 16*(seg ^ (row>>2)).
// Staging (coalesced): lane l -> LDS slot 16*l -> (row=l>>2, global seg =
//   (l&3)^(l>>4)); each aligned group of 4 lanes covers one contiguous 64B
//   global chunk (permuted quarters -> still one cache line).
// Fragment read: lane reads 64*l16 + 16*(quad^(l16>>2)) -> every bank hit
//   exactly 2x per phase; 2-way is free on gfx950 (m136).
//
// K-loop: double-buffered, one barrier per K-step (T3-minimum template):
//   stage(buf^1, k+1) issued BEFORE ds_read+MFMA of buf[k]; the compiler's
//   vmcnt(0)+lgkmcnt(0) at __syncthreads() then waits for loads that had the
//   whole compute phase to land. Never a bare load-wait between two barriers.

// ---------------- grouped GEMM A: act = silu(hs@WgT) * (hs@WuT) ----------------
__global__ __launch_bounds__(256, 2) void gemm_gateup(
    const unsigned short* __restrict__ hs_bf,
    const unsigned short* __restrict__ wg_bf,
    const unsigned short* __restrict__ wu_bf,
    const int* __restrict__ counts,
    const int* __restrict__ offsets,
    const int* __restrict__ token_of,
    unsigned short* __restrict__ act) {
  const int e = blockIdx.z;
  const int cnt = counts[e];
  const int mbase = blockIdx.y * 128;
  if (mbase >= cnt) return;
  const int off0 = offsets[e];
  const int ntile = blockIdx.x;

  __shared__ __align__(16) unsigned short sA[2][128 * 32];
  __shared__ __align__(16) unsigned short sBg[2][128 * 32];
  __shared__ __align__(16) unsigned short sBu[2][128 * 32];
  __shared__ int rb[128];

  const int tid = threadIdx.x;
  const int wave = tid >> 6;
  const int lane = tid & 63;

  if (tid < 128) {
    int slot = off0 + mbase + tid;
    int last = off0 + cnt - 1;
    if (slot > last) slot = last;
    rb[tid] = token_of[slot] * (HIDDEN * 2);
  }
  __syncthreads();

  const int srow0 = wave * 16 + (lane >> 2);
  const int srow1 = srow0 + 64;
  const int colswz = (((lane & 3) ^ (lane >> 4))) * 16;   // swizzled 16B quarter
  const char* pA = (const char*)hs_bf;
  const char* pBg = (const char*)wg_bf + (size_t)e * INTER * HIDDEN * 2;
  const char* pBu = (const char*)wu_bf + (size_t)e * INTER * HIDDEN * 2;
  const long aoff0 = (long)rb[srow0] + colswz;
  const long aoff1 = (long)rb[srow1] + colswz;
  const long boff0 = (long)(ntile * 128 + srow0) * (HIDDEN * 2) + colswz;
  const long boff1 = (long)(ntile * 128 + srow1) * (HIDDEN * 2) + colswz;

  const int lb0 = wave * 512;          // LDS elem offset, rows 0..63 part
  const int lb1 = 2048 + wave * 512;   // rows 64..127 part

  floatx4 accg[4][4], accu[4][4];
  const floatx4 zf = {0.f, 0.f, 0.f, 0.f};
#pragma unroll
  for (int i = 0; i < 4; i++)
#pragma unroll
    for (int j = 0; j < 4; j++) { accg[i][j] = zf; accu[i][j] = zf; }

  const int quad = lane >> 4;
  const int l16 = lane & 15;
  const int wm = (wave >> 1) * 64;
  const int wn = (wave & 1) * 64;
  const int ab = (wave >> 1) * 4;   // A 16-row block base
  const int bb = (wave & 1) * 4;    // B 16-row block base
  const int frg = l16 * 32 + (quad ^ (l16 >> 2)) * 8;  // swizzled fragment offset (elems)

  auto stage = [&](int buf, int kk) {
    const int kb = kk * 64;  // bytes
    async16(pA + aoff0 + kb, &sA[buf][lb0]);
    async16(pA + aoff1 + kb, &sA[buf][lb1]);
    async16(pBg + boff0 + kb, &sBg[buf][lb0]);
    async16(pBg + boff1 + kb, &sBg[buf][lb1]);
    async16(pBu + boff0 + kb, &sBu[buf][lb0]);
    async16(pBu + boff1 + kb, &sBu[buf][lb1]);
  };

  const int NK = HIDDEN / 32;
  stage(0, 0);
  __syncthreads();   // drains vmcnt(0): buf0 ready
  int cur = 0;
  for (int kk = 0; kk < NK; ++kk) {
    if (kk + 1 < NK) stage(cur ^ 1, kk + 1);   // prefetch overlaps compute
    bf16x8 a[4], bg[4], bu[4];
#pragma unroll
    for (int i = 0; i < 4; i++) {
      a[i] = *(const bf16x8*)&sA[cur][(ab + i) * 512 + frg];
      bg[i] = *(const bf16x8*)&sBg[cur][(bb + i) * 512 + frg];
      bu[i] = *(const bf16x8*)&sBu[cur][(bb + i) * 512 + frg];
    }
#pragma unroll
    for (int i = 0; i < 4; i++)
#pragma unroll
      for (int j = 0; j < 4; j++) {
        accg[i][j] = __builtin_amdgcn_mfma_f32_16x16x32_bf16(a[i], bg[j], accg[i][j], 0, 0, 0);
        accu[i][j] = __builtin_amdgcn_mfma_f32_16x16x32_bf16(a[i], bu[j], accu[i][j], 0, 0, 0);
      }
    __syncthreads();   // one barrier/K-step: waits prefetch + read-drain
    cur ^= 1;
  }

  const size_t actrow0 = (size_t)(off0 + mbase);
#pragma unroll
  for (int i = 0; i < 4; i++) {
#pragma unroll
    for (int rr = 0; rr < 4; rr++) {
      const int m = wm + i * 16 + quad * 4 + rr;
      if (mbase + m < cnt) {
        unsigned short* dst = act + (actrow0 + m) * INTER + ntile * 128 + wn + l16;
#pragma unroll
        for (int j = 0; j < 4; j++) {
          float g = accg[i][j][rr];
          float u = accu[i][j][rr];
          float s = g / (1.f + __expf(-g)) * u;
          dst[j * 16] = f2bf(s);
        }
      }
    }
  }
}

// ---------------- grouped GEMM B: slot_out[slot] = w * (act @ WdT) ----------------
__global__ __launch_bounds__(256, 2) void gemm_down(
    const unsigned short* __restrict__ act,
    const unsigned short* __restrict__ wd_bf,
    const int* __restrict__ counts,
    const int* __restrict__ offsets,
    const float* __restrict__ wgt_of,
    float* __restrict__ slot_out) {
  const int e = blockIdx.z;
  const int cnt = counts[e];
  const int mbase = blockIdx.y * 128;
  if (mbase >= cnt) return;
  const int off0 = offsets[e];
  const int ntile = blockIdx.x;

  __shared__ __align__(16) unsigned short sA[2][128 * 32];
  __shared__ __align__(16) unsigned short sB[2][128 * 32];
  __shared__ float wl[128];

  const int tid = threadIdx.x;
  const int wave = tid >> 6;
  const int lane = tid & 63;

  if (tid < 128) {
    int slot = off0 + mbase + tid;
    int last = off0 + cnt - 1;
    if (slot > last) slot = last;
    wl[tid] = wgt_of[slot];
  }
  __syncthreads();

  const int srow0 = wave * 16 + (lane >> 2);
  const int srow1 = srow0 + 64;
  const int colswz = (((lane & 3) ^ (lane >> 4))) * 16;
  const int last = off0 + cnt - 1;
  int s0 = off0 + mbase + srow0; if (s0 > last) s0 = last;
  int s1 = off0 + mbase + srow1; if (s1 > last) s1 = last;
  const char* pA = (const char*)act;
  const char* pB = (const char*)wd_bf + (size_t)e * HIDDEN * INTER * 2;
  const long aoff0 = (long)s0 * (INTER * 2) + colswz;
  const long aoff1 = (long)s1 * (INTER * 2) + colswz;
  const long boff0 = (long)(ntile * 128 + srow0) * (INTER * 2) + colswz;
  const long boff1 = (long)(ntile * 128 + srow1) * (INTER * 2) + colswz;

  const int lb0 = wave * 512;
  const int lb1 = 2048 + wave * 512;

  floatx4 acc[4][4];
  const floatx4 zf = {0.f, 0.f, 0.f, 0.f};
#pragma unroll
  for (int i = 0; i < 4; i++)
#pragma unroll
    for (int j = 0; j < 4; j++) acc[i][j] = zf;

  const int quad = lane >> 4;
  const int l16 = lane & 15;
  const int wm = (wave >> 1) * 64;
  const int wn = (wave & 1) * 64;
  const int ab = (wave >> 1) * 4;
  const int bb = (wave & 1) * 4;
  const int frg = l16 * 32 + (quad ^ (l16 >> 2)) * 8;

  auto stage = [&](int buf, int kk) {
    const int kb = kk * 64;
    async16(pA + aoff0 + kb, &sA[buf][lb0]);
    async16(pA + aoff1 + kb, &sA[buf][lb1]);
    async16(pB + boff0 + kb, &sB[buf][lb0]);
    async16(pB + boff1 + kb, &sB[buf][lb1]);
  };

  const int NK = INTER / 32;
  stage(0, 0);
  __syncthreads();
  int cur = 0;
  for (int kk = 0; kk < NK; ++kk) {
    if (kk + 1 < NK) stage(cur ^ 1, kk + 1);
    bf16x8 a[4], b[4];
#pragma unroll
    for (int i = 0; i < 4; i++) {
      a[i] = *(const bf16x8*)&sA[cur][(ab + i) * 512 + frg];
      b[i] = *(const bf16x8*)&sB[cur][(bb + i) * 512 + frg];
    }
#pragma unroll
    for (int i = 0; i < 4; i++)
#pragma unroll
      for (int j = 0; j < 4; j++)
        acc[i][j] = __builtin_amdgcn_mfma_f32_16x16x32_bf16(a[i], b[j], acc[i][j], 0, 0, 0);
    __syncthreads();
    cur ^= 1;
  }

#pragma unroll
  for (int i = 0; i < 4; i++) {
#pragma unroll
    for (int rr = 0; rr < 4; rr++) {
      const int m = wm + i * 16 + quad * 4 + rr;
      if (mbase + m < cnt) {
        const float w = wl[m];
        float* dst = slot_out + (size_t)(off0 + mbase + m) * HIDDEN + ntile * 128 + wn + l16;
#pragma unroll
        for (int j = 0; j < 4; j++) dst[j * 16] = acc[i][j][rr] * w;
      }
    }
  }
}

// ---------------- combine: out[t] = slot_out[slotA] + slot_out[slotB] ----------------
__global__ void moe_combine(const float* __restrict__ slot_out,
                            const int* __restrict__ slot_of,
                            float* __restrict__ out) {
  const int idx = blockIdx.x * 256 + threadIdx.x;   // TOKENS*256 total
  const int t = idx >> 8;
  const int c4 = idx & 255;
  const int sa = slot_of[t * 2 + 0];
  const int sb = slot_of[t * 2 + 1];
  float4 a = ((const float4*)(slot_out + (size_t)sa * HIDDEN))[c4];
  float4 b = ((const float4*)(slot_out + (size_t)sb * HIDDEN))[c4];
  float4 o;
  o.x = a.x + b.x; o.y = a.y + b.y; o.z = a.z + b.z; o.w = a.w + b.w;
  ((float4*)(out + (size_t)t * HIDDEN))[c4] = o;
}

extern "C" void kernel_launch(void* const* d_in, const int* in_sizes, int n_in,
                              void* d_out, int out_size, void* d_ws, size_t ws_size,
                              hipStream_t stream) {
  const float* hs = (const float*)d_in[0];
  const float* wg = (const float*)d_in[1];
  const float* wgp = (const float*)d_in[2];
  const float* wup = (const float*)d_in[3];
  const float* wdp = (const float*)d_in[4];
  float* out = (float*)d_out;

  char* ws = (char*)d_ws;
  int* counts = (int*)(ws + 0);
  int* cursor = (int*)(ws + 256);
  int* offsets = (int*)(ws + 512);
  int* top_idx = (int*)(ws + 1024);
  float* top_w = (float*)(ws + 1024 + 65536);
  int* token_of = (int*)(ws + 1024 + 2 * 65536);
  float* wgt_of = (float*)(ws + 1024 + 3 * 65536);
  int* slot_of = (int*)(ws + 1024 + 4 * 65536);
  size_t base = 1024 + 5 * 65536;
  unsigned short* hs_bf = (unsigned short*)(ws + base);
  base += (size_t)TOKENS * HIDDEN * 2;
  unsigned short* wg_bf = (unsigned short*)(ws + base);
  base += (size_t)NEXP * INTER * HIDDEN * 2;
  unsigned short* wu_bf = (unsigned short*)(ws + base);
  base += (size_t)NEXP * INTER * HIDDEN * 2;
  unsigned short* wd_bf = (unsigned short*)(ws + base);
  base += (size_t)NEXP * HIDDEN * INTER * 2;
  unsigned short* act = (unsigned short*)(ws + base);
  // slot_out aliases wg_bf/wu_bf (dead after gemm_gateup): 67.1 MB <= 92.3 MB
  float* slot_out = (float*)wg_bf;

  hipMemsetAsync(d_ws, 0, 768, stream);

  cvt_bf16_4<<<dim3(2048, 1, 4), 256, 0, stream>>>(
      hs, hs_bf, TOKENS * HIDDEN / 4,
      wgp, wg_bf, NEXP * INTER * HIDDEN / 4,
      wup, wu_bf, NEXP * INTER * HIDDEN / 4,
      wdp, wd_bf, NEXP * HIDDEN * INTER / 4);

  moe_route<<<TOKENS / 4, 256, 0, stream>>>(hs, wg, counts, top_idx, top_w);
  moe_scan<<<1, 64, 0, stream>>>(counts, offsets, cursor);
  moe_assign<<<TOKENS / 256, 256, 0, stream>>>(top_idx, top_w, cursor, token_of, wgt_of, slot_of);

  dim3 g1(INTER / 128, TOKENS / 128, NEXP);
  gemm_gateup<<<g1, 256, 0, stream>>>(hs_bf, wg_bf, wu_bf, counts, offsets, token_of, act);
  dim3 g2(HIDDEN / 128, TOKENS / 128, NEXP);
  gemm_down<<<g2, 256, 0, stream>>>(act, wd_bf, counts, offsets, wgt_of, slot_out);
  moe_combine<<<TOKENS, 256, 0, stream>>>(slot_out, slot_of, out);
}

// Round 3
// 1005.806 us; speedup vs baseline: 1.0500x; 1.0500x over previous
//
#include <hip/hip_runtime.h>
#include <stdint.h>

#define TOKENS 8192
#define HIDDEN 1024
#define INTER  2816
#define NEXP   8

typedef float floatx4 __attribute__((ext_vector_type(4)));
typedef __bf16 bf16x8 __attribute__((ext_vector_type(8)));

__device__ __forceinline__ unsigned short f2bf(float f) {
  unsigned int u = __float_as_uint(f);
  u += 0x7fffu + ((u >> 16) & 1u);
  return (unsigned short)(u >> 16);
}

__device__ __forceinline__ void async16(const void* g, void* l) {
  __builtin_amdgcn_global_load_lds(
      (const __attribute__((address_space(1))) void*)g,
      (__attribute__((address_space(3))) void*)l, 16, 0, 0);
}

// ---------------- fp32 -> bf16 conversion (4 tensors, one launch) ----------------
__global__ void cvt_bf16_4(const float* __restrict__ s0, unsigned short* __restrict__ d0, int n0,
                           const float* __restrict__ s1, unsigned short* __restrict__ d1, int n1,
                           const float* __restrict__ s2, unsigned short* __restrict__ d2, int n2,
                           const float* __restrict__ s3, unsigned short* __restrict__ d3, int n3) {
  const float* s; unsigned short* d; int n;
  switch (blockIdx.z) {
    case 0: s = s0; d = d0; n = n0; break;
    case 1: s = s1; d = d1; n = n1; break;
    case 2: s = s2; d = d2; n = n2; break;
    default: s = s3; d = d3; n = n3; break;
  }
  int i = blockIdx.x * blockDim.x + threadIdx.x;
  int stride = gridDim.x * blockDim.x;
  for (; i < n; i += stride) {
    float4 v = ((const float4*)s)[i];
    ushort4 o;
    o.x = f2bf(v.x); o.y = f2bf(v.y); o.z = f2bf(v.z); o.w = f2bf(v.w);
    ((ushort4*)d)[i] = o;
  }
}

// ---------------- routing: logits -> top2 -> softmax ----------------
__global__ void moe_route(const float* __restrict__ hs,
                          const float* __restrict__ wg,
                          int* __restrict__ counts,
                          int* __restrict__ top_idx,
                          float* __restrict__ top_w) {
  const int token = blockIdx.x * 4 + (threadIdx.x >> 6);
  const int lane = threadIdx.x & 63;
  const float* row = hs + (size_t)token * HIDDEN;
  float acc[NEXP];
#pragma unroll
  for (int e = 0; e < NEXP; e++) acc[e] = 0.f;
  for (int j = lane; j < HIDDEN; j += 64) {
    float x = row[j];
#pragma unroll
    for (int e = 0; e < NEXP; e++) acc[e] += x * wg[e * HIDDEN + j];
  }
#pragma unroll
  for (int e = 0; e < NEXP; e++) {
    float v = acc[e];
    for (int off = 32; off > 0; off >>= 1) v += __shfl_down(v, off);
    acc[e] = v;
  }
  if (lane == 0) {
    int i0 = 0; float v0 = acc[0];
#pragma unroll
    for (int e = 1; e < NEXP; e++) if (acc[e] > v0) { v0 = acc[e]; i0 = e; }
    int i1 = -1; float v1 = -3.0e38f;
#pragma unroll
    for (int e = 0; e < NEXP; e++) if (e != i0 && acc[e] > v1) { v1 = acc[e]; i1 = e; }
    float e1 = __expf(v1 - v0);
    float s = 1.f + e1;
    top_idx[token * 2 + 0] = i0;
    top_idx[token * 2 + 1] = i1;
    top_w[token * 2 + 0] = 1.f / s;
    top_w[token * 2 + 1] = e1 / s;
    atomicAdd(&counts[i0], 1);
    atomicAdd(&counts[i1], 1);
  }
}

__global__ void moe_scan(const int* __restrict__ counts,
                         int* __restrict__ offsets, int* __restrict__ cursor) {
  if (threadIdx.x == 0) {
    int s = 0;
    for (int e = 0; e < NEXP; e++) { offsets[e] = s; cursor[e] = s; s += counts[e]; }
  }
}

__global__ void moe_assign(const int* __restrict__ top_idx,
                           const float* __restrict__ top_w,
                           int* __restrict__ cursor,
                           int* __restrict__ token_of,
                           float* __restrict__ wgt_of,
                           int* __restrict__ slot_of) {
  const int t = blockIdx.x * 256 + threadIdx.x;
#pragma unroll
  for (int k = 0; k < 2; k++) {
    int e = top_idx[t * 2 + k];
    int pos = atomicAdd(&cursor[e], 1);
    token_of[pos] = t;
    wgt_of[pos] = top_w[t * 2 + k];
    slot_of[t * 2 + k] = pos;
  }
}

// LDS layout: per 16-row block (1024 B), element (row, seg[16B]) lives at
//   64*row + 16*(seg ^ (row>>2)).  (verified layout, unchanged)
//
// K-loop (T4, counted vmcnt): raw s_barrier + per-wave `s_waitcnt vmcnt(N)`
// where N = loads still wanted in flight (next tile's). Each wave waits its
// OWN oldest loads; barrier makes the guarantee collective. sched_barrier(0)
// fences the compute phase so the backend can't hoist ds_reads above the
// barrier (rule #18) or sink MFMAs past the end barrier.
//
// Grid: 1D, wgid&7 = expert = XCD (dispatch round-robins XCDs, m09/m157).
// Within an expert, mtile varies fastest -> all ~16 active blocks sharing one
// B panel run consecutively on ONE XCD -> panel fetched once into that L2
// (was ~8x across XCDs: FETCH_SIZE 476MB vs 108MB working set). Same pinning
// in both GEMMs keeps each expert's `act` in the same XCD's cache path.

// ---------------- grouped GEMM A: act = silu(hs@WgT) * (hs@WuT) ----------------
__global__ __launch_bounds__(256, 2) void gemm_gateup(
    const unsigned short* __restrict__ hs_bf,
    const unsigned short* __restrict__ wg_bf,
    const unsigned short* __restrict__ wu_bf,
    const int* __restrict__ counts,
    const int* __restrict__ offsets,
    const int* __restrict__ token_of,
    unsigned short* __restrict__ act) {
  const int wgid = blockIdx.x;
  const int e = wgid & 7;
  const int idx = wgid >> 3;
  const int ntile = idx / (TOKENS / 128);
  const int mtile = idx % (TOKENS / 128);
  const int cnt = counts[e];
  const int mbase = mtile * 128;
  if (mbase >= cnt) return;
  const int off0 = offsets[e];

  __shared__ __align__(16) unsigned short sA[2][128 * 32];
  __shared__ __align__(16) unsigned short sBg[2][128 * 32];
  __shared__ __align__(16) unsigned short sBu[2][128 * 32];
  __shared__ int rb[128];

  const int tid = threadIdx.x;
  const int wave = tid >> 6;
  const int lane = tid & 63;

  if (tid < 128) {
    int slot = off0 + mbase + tid;
    int last = off0 + cnt - 1;
    if (slot > last) slot = last;
    rb[tid] = token_of[slot] * (HIDDEN * 2);
  }
  __syncthreads();   // full drain: vmcnt==0 entering the pipelined loop

  const int srow0 = wave * 16 + (lane >> 2);
  const int srow1 = srow0 + 64;
  const int colswz = (((lane & 3) ^ (lane >> 4))) * 16;   // swizzled 16B quarter
  const char* pA = (const char*)hs_bf;
  const char* pBg = (const char*)wg_bf + (size_t)e * INTER * HIDDEN * 2;
  const char* pBu = (const char*)wu_bf + (size_t)e * INTER * HIDDEN * 2;
  const long aoff0 = (long)rb[srow0] + colswz;
  const long aoff1 = (long)rb[srow1] + colswz;
  const long boff0 = (long)(ntile * 128 + srow0) * (HIDDEN * 2) + colswz;
  const long boff1 = (long)(ntile * 128 + srow1) * (HIDDEN * 2) + colswz;

  const int lb0 = wave * 512;          // LDS elem offset, rows 0..63 part
  const int lb1 = 2048 + wave * 512;   // rows 64..127 part

  floatx4 accg[4][4], accu[4][4];
  const floatx4 zf = {0.f, 0.f, 0.f, 0.f};
#pragma unroll
  for (int i = 0; i < 4; i++)
#pragma unroll
    for (int j = 0; j < 4; j++) { accg[i][j] = zf; accu[i][j] = zf; }

  const int quad = lane >> 4;
  const int l16 = lane & 15;
  const int wm = (wave >> 1) * 64;
  const int wn = (wave & 1) * 64;
  const int ab = (wave >> 1) * 4;   // A 16-row block base
  const int bb = (wave & 1) * 4;    // B 16-row block base
  const int frg = l16 * 32 + (quad ^ (l16 >> 2)) * 8;  // swizzled fragment offset (elems)

  auto stage = [&](int buf, int kk) {
    const int kb = kk * 64;  // bytes
    async16(pA + aoff0 + kb, &sA[buf][lb0]);
    async16(pA + aoff1 + kb, &sA[buf][lb1]);
    async16(pBg + boff0 + kb, &sBg[buf][lb0]);
    async16(pBg + boff1 + kb, &sBg[buf][lb1]);
    async16(pBu + boff0 + kb, &sBu[buf][lb0]);
    async16(pBu + boff1 + kb, &sBu[buf][lb1]);
  };

  const int NK = HIDDEN / 32;
  stage(0, 0);   // 6 loads in flight
  int cur = 0;
  for (int kk = 0; kk < NK; ++kk) {
    if (kk + 1 < NK) {
      stage(cur ^ 1, kk + 1);                       // 12 in flight
      asm volatile("s_waitcnt vmcnt(6)" ::: "memory");  // oldest 6 (buf[cur]) landed
    } else {
      asm volatile("s_waitcnt vmcnt(0)" ::: "memory");
    }
    __builtin_amdgcn_s_barrier();                   // collective: buf[cur] ready
    __builtin_amdgcn_sched_barrier(0);
    bf16x8 a[4], bg[4], bu[4];
#pragma unroll
    for (int i = 0; i < 4; i++) {
      a[i] = *(const bf16x8*)&sA[cur][(ab + i) * 512 + frg];
      bg[i] = *(const bf16x8*)&sBg[cur][(bb + i) * 512 + frg];
      bu[i] = *(const bf16x8*)&sBu[cur][(bb + i) * 512 + frg];
    }
#pragma unroll
    for (int i = 0; i < 4; i++)
#pragma unroll
      for (int j = 0; j < 4; j++) {
        accg[i][j] = __builtin_amdgcn_mfma_f32_16x16x32_bf16(a[i], bg[j], accg[i][j], 0, 0, 0);
        accu[i][j] = __builtin_amdgcn_mfma_f32_16x16x32_bf16(a[i], bu[j], accu[i][j], 0, 0, 0);
      }
    __builtin_amdgcn_sched_barrier(0);
    __builtin_amdgcn_s_barrier();                   // all reads of buf[cur] done
    cur ^= 1;
  }

  const size_t actrow0 = (size_t)(off0 + mbase);
#pragma unroll
  for (int i = 0; i < 4; i++) {
#pragma unroll
    for (int rr = 0; rr < 4; rr++) {
      const int m = wm + i * 16 + quad * 4 + rr;
      if (mbase + m < cnt) {
        unsigned short* dst = act + (actrow0 + m) * INTER + ntile * 128 + wn + l16;
#pragma unroll
        for (int j = 0; j < 4; j++) {
          float g = accg[i][j][rr];
          float u = accu[i][j][rr];
          float s = g / (1.f + __expf(-g)) * u;
          dst[j * 16] = f2bf(s);
        }
      }
    }
  }
}

// ---------------- grouped GEMM B: slot_out[slot] = w * (act @ WdT) ----------------
__global__ __launch_bounds__(256, 2) void gemm_down(
    const unsigned short* __restrict__ act,
    const unsigned short* __restrict__ wd_bf,
    const int* __restrict__ counts,
    const int* __restrict__ offsets,
    const float* __restrict__ wgt_of,
    float* __restrict__ slot_out) {
  const int wgid = blockIdx.x;
  const int e = wgid & 7;
  const int idx = wgid >> 3;
  const int ntile = idx / (TOKENS / 128);
  const int mtile = idx % (TOKENS / 128);
  const int cnt = counts[e];
  const int mbase = mtile * 128;
  if (mbase >= cnt) return;
  const int off0 = offsets[e];

  __shared__ __align__(16) unsigned short sA[2][128 * 32];
  __shared__ __align__(16) unsigned short sB[2][128 * 32];
  __shared__ float wl[128];

  const int tid = threadIdx.x;
  const int wave = tid >> 6;
  const int lane = tid & 63;

  if (tid < 128) {
    int slot = off0 + mbase + tid;
    int last = off0 + cnt - 1;
    if (slot > last) slot = last;
    wl[tid] = wgt_of[slot];
  }
  __syncthreads();   // full drain before pipelined loop

  const int srow0 = wave * 16 + (lane >> 2);
  const int srow1 = srow0 + 64;
  const int colswz = (((lane & 3) ^ (lane >> 4))) * 16;
  const int last = off0 + cnt - 1;
  int s0 = off0 + mbase + srow0; if (s0 > last) s0 = last;
  int s1 = off0 + mbase + srow1; if (s1 > last) s1 = last;
  const char* pA = (const char*)act;
  const char* pB = (const char*)wd_bf + (size_t)e * HIDDEN * INTER * 2;
  const long aoff0 = (long)s0 * (INTER * 2) + colswz;
  const long aoff1 = (long)s1 * (INTER * 2) + colswz;
  const long boff0 = (long)(ntile * 128 + srow0) * (INTER * 2) + colswz;
  const long boff1 = (long)(ntile * 128 + srow1) * (INTER * 2) + colswz;

  const int lb0 = wave * 512;
  const int lb1 = 2048 + wave * 512;

  floatx4 acc[4][4];
  const floatx4 zf = {0.f, 0.f, 0.f, 0.f};
#pragma unroll
  for (int i = 0; i < 4; i++)
#pragma unroll
    for (int j = 0; j < 4; j++) acc[i][j] = zf;

  const int quad = lane >> 4;
  const int l16 = lane & 15;
  const int wm = (wave >> 1) * 64;
  const int wn = (wave & 1) * 64;
  const int ab = (wave >> 1) * 4;
  const int bb = (wave & 1) * 4;
  const int frg = l16 * 32 + (quad ^ (l16 >> 2)) * 8;

  auto stage = [&](int buf, int kk) {
    const int kb = kk * 64;
    async16(pA + aoff0 + kb, &sA[buf][lb0]);
    async16(pA + aoff1 + kb, &sA[buf][lb1]);
    async16(pB + boff0 + kb, &sB[buf][lb0]);
    async16(pB + boff1 + kb, &sB[buf][lb1]);
  };

  const int NK = INTER / 32;
  stage(0, 0);   // 4 loads in flight
  int cur = 0;
  for (int kk = 0; kk < NK; ++kk) {
    if (kk + 1 < NK) {
      stage(cur ^ 1, kk + 1);                       // 8 in flight
      asm volatile("s_waitcnt vmcnt(4)" ::: "memory");
    } else {
      asm volatile("s_waitcnt vmcnt(0)" ::: "memory");
    }
    __builtin_amdgcn_s_barrier();
    __builtin_amdgcn_sched_barrier(0);
    bf16x8 a[4], b[4];
#pragma unroll
    for (int i = 0; i < 4; i++) {
      a[i] = *(const bf16x8*)&sA[cur][(ab + i) * 512 + frg];
      b[i] = *(const bf16x8*)&sB[cur][(bb + i) * 512 + frg];
    }
#pragma unroll
    for (int i = 0; i < 4; i++)
#pragma unroll
      for (int j = 0; j < 4; j++)
        acc[i][j] = __builtin_amdgcn_mfma_f32_16x16x32_bf16(a[i], b[j], acc[i][j], 0, 0, 0);
    __builtin_amdgcn_sched_barrier(0);
    __builtin_amdgcn_s_barrier();
    cur ^= 1;
  }

#pragma unroll
  for (int i = 0; i < 4; i++) {
#pragma unroll
    for (int rr = 0; rr < 4; rr++) {
      const int m = wm + i * 16 + quad * 4 + rr;
      if (mbase + m < cnt) {
        const float w = wl[m];
        float* dst = slot_out + (size_t)(off0 + mbase + m) * HIDDEN + ntile * 128 + wn + l16;
#pragma unroll
        for (int j = 0; j < 4; j++) dst[j * 16] = acc[i][j][rr] * w;
      }
    }
  }
}

// ---------------- combine: out[t] = slot_out[slotA] + slot_out[slotB] ----------------
__global__ void moe_combine(const float* __restrict__ slot_out,
                            const int* __restrict__ slot_of,
                            float* __restrict__ out) {
  const int idx = blockIdx.x * 256 + threadIdx.x;   // TOKENS*256 total
  const int t = idx >> 8;
  const int c4 = idx & 255;
  const int sa = slot_of[t * 2 + 0];
  const int sb = slot_of[t * 2 + 1];
  float4 a = ((const float4*)(slot_out + (size_t)sa * HIDDEN))[c4];
  float4 b = ((const float4*)(slot_out + (size_t)sb * HIDDEN))[c4];
  float4 o;
  o.x = a.x + b.x; o.y = a.y + b.y; o.z = a.z + b.z; o.w = a.w + b.w;
  ((float4*)(out + (size_t)t * HIDDEN))[c4] = o;
}

extern "C" void kernel_launch(void* const* d_in, const int* in_sizes, int n_in,
                              void* d_out, int out_size, void* d_ws, size_t ws_size,
                              hipStream_t stream) {
  const float* hs = (const float*)d_in[0];
  const float* wg = (const float*)d_in[1];
  const float* wgp = (const float*)d_in[2];
  const float* wup = (const float*)d_in[3];
  const float* wdp = (const float*)d_in[4];
  float* out = (float*)d_out;

  char* ws = (char*)d_ws;
  int* counts = (int*)(ws + 0);
  int* cursor = (int*)(ws + 256);
  int* offsets = (int*)(ws + 512);
  int* top_idx = (int*)(ws + 1024);
  float* top_w = (float*)(ws + 1024 + 65536);
  int* token_of = (int*)(ws + 1024 + 2 * 65536);
  float* wgt_of = (float*)(ws + 1024 + 3 * 65536);
  int* slot_of = (int*)(ws + 1024 + 4 * 65536);
  size_t base = 1024 + 5 * 65536;
  unsigned short* hs_bf = (unsigned short*)(ws + base);
  base += (size_t)TOKENS * HIDDEN * 2;
  unsigned short* wg_bf = (unsigned short*)(ws + base);
  base += (size_t)NEXP * INTER * HIDDEN * 2;
  unsigned short* wu_bf = (unsigned short*)(ws + base);
  base += (size_t)NEXP * INTER * HIDDEN * 2;
  unsigned short* wd_bf = (unsigned short*)(ws + base);
  base += (size_t)NEXP * HIDDEN * INTER * 2;
  unsigned short* act = (unsigned short*)(ws + base);
  // slot_out aliases wg_bf/wu_bf (dead after gemm_gateup): 67.1 MB <= 92.3 MB
  float* slot_out = (float*)wg_bf;

  hipMemsetAsync(d_ws, 0, 768, stream);

  cvt_bf16_4<<<dim3(2048, 1, 4), 256, 0, stream>>>(
      hs, hs_bf, TOKENS * HIDDEN / 4,
      wgp, wg_bf, NEXP * INTER * HIDDEN / 4,
      wup, wu_bf, NEXP * INTER * HIDDEN / 4,
      wdp, wd_bf, NEXP * HIDDEN * INTER / 4);

  moe_route<<<TOKENS / 4, 256, 0, stream>>>(hs, wg, counts, top_idx, top_w);
  moe_scan<<<1, 64, 0, stream>>>(counts, offsets, cursor);
  moe_assign<<<TOKENS / 256, 256, 0, stream>>>(top_idx, top_w, cursor, token_of, wgt_of, slot_of);

  // 1D grids: wgid&7 = expert (XCD-pinned), mtile fastest (same-B consecutive)
  gemm_gateup<<<dim3((INTER / 128) * (TOKENS / 128) * NEXP), 256, 0, stream>>>(
      hs_bf, wg_bf, wu_bf, counts, offsets, token_of, act);
  gemm_down<<<dim3((HIDDEN / 128) * (TOKENS / 128) * NEXP), 256, 0, stream>>>(
      act, wd_bf, counts, offsets, wgt_of, slot_out);
  moe_combine<<<TOKENS, 256, 0, stream>>>(slot_out, slot_of, out);
}

// Round 4
// 998.734 us; speedup vs baseline: 1.0574x; 1.0071x over previous
//
#include <hip/hip_runtime.h>
#include <stdint.h>

#define TOKENS 8192
#define HIDDEN 1024
#define INTER  2816
#define NEXP   8

typedef float floatx4 __attribute__((ext_vector_type(4)));
typedef __bf16 bf16x8 __attribute__((ext_vector_type(8)));

__device__ __forceinline__ unsigned short f2bf(float f) {
  unsigned int u = __float_as_uint(f);
  u += 0x7fffu + ((u >> 16) & 1u);
  return (unsigned short)(u >> 16);
}

__device__ __forceinline__ void async16(const void* g, void* l) {
  __builtin_amdgcn_global_load_lds(
      (const __attribute__((address_space(1))) void*)g,
      (__attribute__((address_space(3))) void*)l, 16, 0, 0);
}

// ---------------- fp32 -> bf16 conversion (4 tensors, one launch) ----------------
__global__ void cvt_bf16_4(const float* __restrict__ s0, unsigned short* __restrict__ d0, int n0,
                           const float* __restrict__ s1, unsigned short* __restrict__ d1, int n1,
                           const float* __restrict__ s2, unsigned short* __restrict__ d2, int n2,
                           const float* __restrict__ s3, unsigned short* __restrict__ d3, int n3) {
  const float* s; unsigned short* d; int n;
  switch (blockIdx.z) {
    case 0: s = s0; d = d0; n = n0; break;
    case 1: s = s1; d = d1; n = n1; break;
    case 2: s = s2; d = d2; n = n2; break;
    default: s = s3; d = d3; n = n3; break;
  }
  int i = blockIdx.x * blockDim.x + threadIdx.x;
  int stride = gridDim.x * blockDim.x;
  for (; i < n; i += stride) {
    float4 v = ((const float4*)s)[i];
    ushort4 o;
    o.x = f2bf(v.x); o.y = f2bf(v.y); o.z = f2bf(v.z); o.w = f2bf(v.w);
    ((ushort4*)d)[i] = o;
  }
}

// ---------------- routing: logits -> top2 -> softmax ----------------
__global__ void moe_route(const float* __restrict__ hs,
                          const float* __restrict__ wg,
                          int* __restrict__ counts,
                          int* __restrict__ top_idx,
                          float* __restrict__ top_w) {
  const int token = blockIdx.x * 4 + (threadIdx.x >> 6);
  const int lane = threadIdx.x & 63;
  const float* row = hs + (size_t)token * HIDDEN;
  float acc[NEXP];
#pragma unroll
  for (int e = 0; e < NEXP; e++) acc[e] = 0.f;
  for (int j = lane; j < HIDDEN; j += 64) {
    float x = row[j];
#pragma unroll
    for (int e = 0; e < NEXP; e++) acc[e] += x * wg[e * HIDDEN + j];
  }
#pragma unroll
  for (int e = 0; e < NEXP; e++) {
    float v = acc[e];
    for (int off = 32; off > 0; off >>= 1) v += __shfl_down(v, off);
    acc[e] = v;
  }
  if (lane == 0) {
    int i0 = 0; float v0 = acc[0];
#pragma unroll
    for (int e = 1; e < NEXP; e++) if (acc[e] > v0) { v0 = acc[e]; i0 = e; }
    int i1 = -1; float v1 = -3.0e38f;
#pragma unroll
    for (int e = 0; e < NEXP; e++) if (e != i0 && acc[e] > v1) { v1 = acc[e]; i1 = e; }
    float e1 = __expf(v1 - v0);
    float s = 1.f + e1;
    top_idx[token * 2 + 0] = i0;
    top_idx[token * 2 + 1] = i1;
    top_w[token * 2 + 0] = 1.f / s;
    top_w[token * 2 + 1] = e1 / s;
    atomicAdd(&counts[i0], 1);
    atomicAdd(&counts[i1], 1);
  }
}

__global__ void moe_scan(const int* __restrict__ counts,
                         int* __restrict__ offsets, int* __restrict__ cursor) {
  if (threadIdx.x == 0) {
    int s = 0;
    for (int e = 0; e < NEXP; e++) { offsets[e] = s; cursor[e] = s; s += counts[e]; }
  }
}

__global__ void moe_assign(const int* __restrict__ top_idx,
                           const float* __restrict__ top_w,
                           int* __restrict__ cursor,
                           int* __restrict__ token_of,
                           float* __restrict__ wgt_of,
                           int* __restrict__ slot_of) {
  const int t = blockIdx.x * 256 + threadIdx.x;
#pragma unroll
  for (int k = 0; k < 2; k++) {
    int e = top_idx[t * 2 + k];
    int pos = atomicAdd(&cursor[e], 1);
    token_of[pos] = t;
    wgt_of[pos] = top_w[t * 2 + k];
    slot_of[t * 2 + k] = pos;
  }
}

// LDS layout (unchanged, verified): per 16-row block (1024 B), element
//   (row, seg[16B]) at 64*row + 16*(seg ^ (row>>2)).
//
// K-loop (T4, DEPTH-2 prefetch, 3-buffer ring): at step k, stage buf[(k+2)%3],
// wait `vmcnt(2*S)` (S = loads/stage) so only step-k's loads must have landed;
// two full compute phases (~800-1200 cyc) cover HBM-miss latency (~900 cyc),
// which depth-1 (R3, one ~400-600 cyc phase) did not — that was the measured
// stall (MfmaUtil 28%, all counters low). WAR safety: buf[(k+2)%3] ==
// buf[(k-1)%3], whose reads retired before step k-1's end barrier.
//
// Grid: 1D, wgid&7 = expert = XCD (kept from R3: FETCH_SIZE 476->160 MB).

// ---------------- grouped GEMM A: act = silu(hs@WgT) * (hs@WuT) ----------------
__global__ __launch_bounds__(256, 2) void gemm_gateup(
    const unsigned short* __restrict__ hs_bf,
    const unsigned short* __restrict__ wg_bf,
    const unsigned short* __restrict__ wu_bf,
    const int* __restrict__ counts,
    const int* __restrict__ offsets,
    const int* __restrict__ token_of,
    unsigned short* __restrict__ act) {
  const int wgid = blockIdx.x;
  const int e = wgid & 7;
  const int idx = wgid >> 3;
  const int ntile = idx / (TOKENS / 128);
  const int mtile = idx % (TOKENS / 128);
  const int cnt = counts[e];
  const int mbase = mtile * 128;
  if (mbase >= cnt) return;
  const int off0 = offsets[e];

  __shared__ __align__(16) unsigned short sA[3][128 * 32];
  __shared__ __align__(16) unsigned short sBg[3][128 * 32];
  __shared__ __align__(16) unsigned short sBu[3][128 * 32];
  __shared__ int rb[128];

  const int tid = threadIdx.x;
  const int wave = tid >> 6;
  const int lane = tid & 63;

  if (tid < 128) {
    int slot = off0 + mbase + tid;
    int last = off0 + cnt - 1;
    if (slot > last) slot = last;
    rb[tid] = token_of[slot] * (HIDDEN * 2);
  }
  __syncthreads();   // full drain: vmcnt==0 entering the pipelined loop

  const int srow0 = wave * 16 + (lane >> 2);
  const int srow1 = srow0 + 64;
  const int colswz = (((lane & 3) ^ (lane >> 4))) * 16;   // swizzled 16B quarter
  const char* pA = (const char*)hs_bf;
  const char* pBg = (const char*)wg_bf + (size_t)e * INTER * HIDDEN * 2;
  const char* pBu = (const char*)wu_bf + (size_t)e * INTER * HIDDEN * 2;
  const long aoff0 = (long)rb[srow0] + colswz;
  const long aoff1 = (long)rb[srow1] + colswz;
  const long boff0 = (long)(ntile * 128 + srow0) * (HIDDEN * 2) + colswz;
  const long boff1 = (long)(ntile * 128 + srow1) * (HIDDEN * 2) + colswz;

  const int lb0 = wave * 512;          // LDS elem offset, rows 0..63 part
  const int lb1 = 2048 + wave * 512;   // rows 64..127 part

  floatx4 accg[4][4], accu[4][4];
  const floatx4 zf = {0.f, 0.f, 0.f, 0.f};
#pragma unroll
  for (int i = 0; i < 4; i++)
#pragma unroll
    for (int j = 0; j < 4; j++) { accg[i][j] = zf; accu[i][j] = zf; }

  const int quad = lane >> 4;
  const int l16 = lane & 15;
  const int wm = (wave >> 1) * 64;
  const int wn = (wave & 1) * 64;
  const int ab = (wave >> 1) * 4;   // A 16-row block base
  const int bb = (wave & 1) * 4;    // B 16-row block base
  const int frg = l16 * 32 + (quad ^ (l16 >> 2)) * 8;  // swizzled fragment offset (elems)

  auto stage = [&](int buf, int kk) {
    const int kb = kk * 64;  // bytes
    async16(pA + aoff0 + kb, &sA[buf][lb0]);
    async16(pA + aoff1 + kb, &sA[buf][lb1]);
    async16(pBg + boff0 + kb, &sBg[buf][lb0]);
    async16(pBg + boff1 + kb, &sBg[buf][lb1]);
    async16(pBu + boff0 + kb, &sBu[buf][lb0]);
    async16(pBu + boff1 + kb, &sBu[buf][lb1]);
  };

  const int NK = HIDDEN / 32;
  stage(0, 0);
  stage(1, 1);   // 12 loads in flight, 2 K-steps deep
  int cur = 0;
  for (int kk = 0; kk < NK; ++kk) {
    if (kk + 2 < NK) {
      int pre = cur + 2; if (pre >= 3) pre -= 3;
      stage(pre, kk + 2);                               // 18 in flight
      asm volatile("s_waitcnt vmcnt(12)" ::: "memory"); // oldest 6 (step kk) landed
    } else if (kk + 1 < NK) {
      asm volatile("s_waitcnt vmcnt(6)" ::: "memory");
    } else {
      asm volatile("s_waitcnt vmcnt(0)" ::: "memory");
    }
    __builtin_amdgcn_s_barrier();                   // collective: buf[cur] ready
    __builtin_amdgcn_sched_barrier(0);
    bf16x8 a[4], bg[4], bu[4];
#pragma unroll
    for (int i = 0; i < 4; i++) {
      a[i] = *(const bf16x8*)&sA[cur][(ab + i) * 512 + frg];
      bg[i] = *(const bf16x8*)&sBg[cur][(bb + i) * 512 + frg];
      bu[i] = *(const bf16x8*)&sBu[cur][(bb + i) * 512 + frg];
    }
#pragma unroll
    for (int i = 0; i < 4; i++)
#pragma unroll
      for (int j = 0; j < 4; j++) {
        accg[i][j] = __builtin_amdgcn_mfma_f32_16x16x32_bf16(a[i], bg[j], accg[i][j], 0, 0, 0);
        accu[i][j] = __builtin_amdgcn_mfma_f32_16x16x32_bf16(a[i], bu[j], accu[i][j], 0, 0, 0);
      }
    __builtin_amdgcn_sched_barrier(0);
    __builtin_amdgcn_s_barrier();                   // all reads of buf[cur] done
    cur = cur + 1; if (cur >= 3) cur = 0;
  }

  const size_t actrow0 = (size_t)(off0 + mbase);
#pragma unroll
  for (int i = 0; i < 4; i++) {
#pragma unroll
    for (int rr = 0; rr < 4; rr++) {
      const int m = wm + i * 16 + quad * 4 + rr;
      if (mbase + m < cnt) {
        unsigned short* dst = act + (actrow0 + m) * INTER + ntile * 128 + wn + l16;
#pragma unroll
        for (int j = 0; j < 4; j++) {
          float g = accg[i][j][rr];
          float u = accu[i][j][rr];
          float s = g / (1.f + __expf(-g)) * u;
          dst[j * 16] = f2bf(s);
        }
      }
    }
  }
}

// ---------------- grouped GEMM B: slot_out[slot] = w * (act @ WdT) ----------------
__global__ __launch_bounds__(256, 3) void gemm_down(
    const unsigned short* __restrict__ act,
    const unsigned short* __restrict__ wd_bf,
    const int* __restrict__ counts,
    const int* __restrict__ offsets,
    const float* __restrict__ wgt_of,
    float* __restrict__ slot_out) {
  const int wgid = blockIdx.x;
  const int e = wgid & 7;
  const int idx = wgid >> 3;
  const int ntile = idx / (TOKENS / 128);
  const int mtile = idx % (TOKENS / 128);
  const int cnt = counts[e];
  const int mbase = mtile * 128;
  if (mbase >= cnt) return;
  const int off0 = offsets[e];

  __shared__ __align__(16) unsigned short sA[3][128 * 32];
  __shared__ __align__(16) unsigned short sB[3][128 * 32];
  __shared__ float wl[128];

  const int tid = threadIdx.x;
  const int wave = tid >> 6;
  const int lane = tid & 63;

  if (tid < 128) {
    int slot = off0 + mbase + tid;
    int last = off0 + cnt - 1;
    if (slot > last) slot = last;
    wl[tid] = wgt_of[slot];
  }
  __syncthreads();   // full drain before pipelined loop

  const int srow0 = wave * 16 + (lane >> 2);
  const int srow1 = srow0 + 64;
  const int colswz = (((lane & 3) ^ (lane >> 4))) * 16;
  const int last = off0 + cnt - 1;
  int s0 = off0 + mbase + srow0; if (s0 > last) s0 = last;
  int s1 = off0 + mbase + srow1; if (s1 > last) s1 = last;
  const char* pA = (const char*)act;
  const char* pB = (const char*)wd_bf + (size_t)e * HIDDEN * INTER * 2;
  const long aoff0 = (long)s0 * (INTER * 2) + colswz;
  const long aoff1 = (long)s1 * (INTER * 2) + colswz;
  const long boff0 = (long)(ntile * 128 + srow0) * (INTER * 2) + colswz;
  const long boff1 = (long)(ntile * 128 + srow1) * (INTER * 2) + colswz;

  const int lb0 = wave * 512;
  const int lb1 = 2048 + wave * 512;

  floatx4 acc[4][4];
  const floatx4 zf = {0.f, 0.f, 0.f, 0.f};
#pragma unroll
  for (int i = 0; i < 4; i++)
#pragma unroll
    for (int j = 0; j < 4; j++) acc[i][j] = zf;

  const int quad = lane >> 4;
  const int l16 = lane & 15;
  const int wm = (wave >> 1) * 64;
  const int wn = (wave & 1) * 64;
  const int ab = (wave >> 1) * 4;
  const int bb = (wave & 1) * 4;
  const int frg = l16 * 32 + (quad ^ (l16 >> 2)) * 8;

  auto stage = [&](int buf, int kk) {
    const int kb = kk * 64;
    async16(pA + aoff0 + kb, &sA[buf][lb0]);
    async16(pA + aoff1 + kb, &sA[buf][lb1]);
    async16(pB + boff0 + kb, &sB[buf][lb0]);
    async16(pB + boff1 + kb, &sB[buf][lb1]);
  };

  const int NK = INTER / 32;
  stage(0, 0);
  stage(1, 1);   // 8 loads in flight, 2 K-steps deep
  int cur = 0;
  for (int kk = 0; kk < NK; ++kk) {
    if (kk + 2 < NK) {
      int pre = cur + 2; if (pre >= 3) pre -= 3;
      stage(pre, kk + 2);                              // 12 in flight
      asm volatile("s_waitcnt vmcnt(8)" ::: "memory"); // oldest 4 (step kk) landed
    } else if (kk + 1 < NK) {
      asm volatile("s_waitcnt vmcnt(4)" ::: "memory");
    } else {
      asm volatile("s_waitcnt vmcnt(0)" ::: "memory");
    }
    __builtin_amdgcn_s_barrier();
    __builtin_amdgcn_sched_barrier(0);
    bf16x8 a[4], b[4];
#pragma unroll
    for (int i = 0; i < 4; i++) {
      a[i] = *(const bf16x8*)&sA[cur][(ab + i) * 512 + frg];
      b[i] = *(const bf16x8*)&sB[cur][(bb + i) * 512 + frg];
    }
#pragma unroll
    for (int i = 0; i < 4; i++)
#pragma unroll
      for (int j = 0; j < 4; j++)
        acc[i][j] = __builtin_amdgcn_mfma_f32_16x16x32_bf16(a[i], b[j], acc[i][j], 0, 0, 0);
    __builtin_amdgcn_sched_barrier(0);
    __builtin_amdgcn_s_barrier();
    cur = cur + 1; if (cur >= 3) cur = 0;
  }

#pragma unroll
  for (int i = 0; i < 4; i++) {
#pragma unroll
    for (int rr = 0; rr < 4; rr++) {
      const int m = wm + i * 16 + quad * 4 + rr;
      if (mbase + m < cnt) {
        const float w = wl[m];
        float* dst = slot_out + (size_t)(off0 + mbase + m) * HIDDEN + ntile * 128 + wn + l16;
#pragma unroll
        for (int j = 0; j < 4; j++) dst[j * 16] = acc[i][j][rr] * w;
      }
    }
  }
}

// ---------------- combine: out[t] = slot_out[slotA] + slot_out[slotB] ----------------
__global__ void moe_combine(const float* __restrict__ slot_out,
                            const int* __restrict__ slot_of,
                            float* __restrict__ out) {
  const int idx = blockIdx.x * 256 + threadIdx.x;   // TOKENS*256 total
  const int t = idx >> 8;
  const int c4 = idx & 255;
  const int sa = slot_of[t * 2 + 0];
  const int sb = slot_of[t * 2 + 1];
  float4 a = ((const float4*)(slot_out + (size_t)sa * HIDDEN))[c4];
  float4 b = ((const float4*)(slot_out + (size_t)sb * HIDDEN))[c4];
  float4 o;
  o.x = a.x + b.x; o.y = a.y + b.y; o.z = a.z + b.z; o.w = a.w + b.w;
  ((float4*)(out + (size_t)t * HIDDEN))[c4] = o;
}

extern "C" void kernel_launch(void* const* d_in, const int* in_sizes, int n_in,
                              void* d_out, int out_size, void* d_ws, size_t ws_size,
                              hipStream_t stream) {
  const float* hs = (const float*)d_in[0];
  const float* wg = (const float*)d_in[1];
  const float* wgp = (const float*)d_in[2];
  const float* wup = (const float*)d_in[3];
  const float* wdp = (const float*)d_in[4];
  float* out = (float*)d_out;

  char* ws = (char*)d_ws;
  int* counts = (int*)(ws + 0);
  int* cursor = (int*)(ws + 256);
  int* offsets = (int*)(ws + 512);
  int* top_idx = (int*)(ws + 1024);
  float* top_w = (float*)(ws + 1024 + 65536);
  int* token_of = (int*)(ws + 1024 + 2 * 65536);
  float* wgt_of = (float*)(ws + 1024 + 3 * 65536);
  int* slot_of = (int*)(ws + 1024 + 4 * 65536);
  size_t base = 1024 + 5 * 65536;
  unsigned short* hs_bf = (unsigned short*)(ws + base);
  base += (size_t)TOKENS * HIDDEN * 2;
  unsigned short* wg_bf = (unsigned short*)(ws + base);
  base += (size_t)NEXP * INTER * HIDDEN * 2;
  unsigned short* wu_bf = (unsigned short*)(ws + base);
  base += (size_t)NEXP * INTER * HIDDEN * 2;
  unsigned short* wd_bf = (unsigned short*)(ws + base);
  base += (size_t)NEXP * HIDDEN * INTER * 2;
  unsigned short* act = (unsigned short*)(ws + base);
  // slot_out aliases wg_bf/wu_bf (dead after gemm_gateup): 67.1 MB <= 92.3 MB
  float* slot_out = (float*)wg_bf;

  hipMemsetAsync(d_ws, 0, 768, stream);

  cvt_bf16_4<<<dim3(2048, 1, 4), 256, 0, stream>>>(
      hs, hs_bf, TOKENS * HIDDEN / 4,
      wgp, wg_bf, NEXP * INTER * HIDDEN / 4,
      wup, wu_bf, NEXP * INTER * HIDDEN / 4,
      wdp, wd_bf, NEXP * HIDDEN * INTER / 4);

  moe_route<<<TOKENS / 4, 256, 0, stream>>>(hs, wg, counts, top_idx, top_w);
  moe_scan<<<1, 64, 0, stream>>>(counts, offsets, cursor);
  moe_assign<<<TOKENS / 256, 256, 0, stream>>>(top_idx, top_w, cursor, token_of, wgt_of, slot_of);

  // 1D grids: wgid&7 = expert (XCD-pinned), mtile fastest (same-B consecutive)
  gemm_gateup<<<dim3((INTER / 128) * (TOKENS / 128) * NEXP), 256, 0, stream>>>(
      hs_bf, wg_bf, wu_bf, counts, offsets, token_of, act);
  gemm_down<<<dim3((HIDDEN / 128) * (TOKENS / 128) * NEXP), 256, 0, stream>>>(
      act, wd_bf, counts, offsets, wgt_of, slot_out);
  moe_combine<<<TOKENS, 256, 0, stream>>>(slot_out, slot_of, out);
}

// Round 5
// 756.516 us; speedup vs baseline: 1.3960x; 1.3202x over previous
//
#include <hip/hip_runtime.h>
#include <stdint.h>

#define TOKENS 8192
#define HIDDEN 1024
#define INTER  2816
#define NEXP   8

typedef float floatx4 __attribute__((ext_vector_type(4)));
typedef __bf16 bf16x8 __attribute__((ext_vector_type(8)));

__device__ __forceinline__ unsigned short f2bf(float f) {
  unsigned int u = __float_as_uint(f);
  u += 0x7fffu + ((u >> 16) & 1u);
  return (unsigned short)(u >> 16);
}

__device__ __forceinline__ void async16(const void* g, void* l) {
  __builtin_amdgcn_global_load_lds(
      (const __attribute__((address_space(1))) void*)g,
      (__attribute__((address_space(3))) void*)l, 16, 0, 0);
}

// ---------------- fp32 -> bf16 conversion (4 tensors, one launch) ----------------
__global__ void cvt_bf16_4(const float* __restrict__ s0, unsigned short* __restrict__ d0, int n0,
                           const float* __restrict__ s1, unsigned short* __restrict__ d1, int n1,
                           const float* __restrict__ s2, unsigned short* __restrict__ d2, int n2,
                           const float* __restrict__ s3, unsigned short* __restrict__ d3, int n3) {
  const float* s; unsigned short* d; int n;
  switch (blockIdx.z) {
    case 0: s = s0; d = d0; n = n0; break;
    case 1: s = s1; d = d1; n = n1; break;
    case 2: s = s2; d = d2; n = n2; break;
    default: s = s3; d = d3; n = n3; break;
  }
  int i = blockIdx.x * blockDim.x + threadIdx.x;
  int stride = gridDim.x * blockDim.x;
  for (; i < n; i += stride) {
    float4 v = ((const float4*)s)[i];
    ushort4 o;
    o.x = f2bf(v.x); o.y = f2bf(v.y); o.z = f2bf(v.z); o.w = f2bf(v.w);
    ((ushort4*)d)[i] = o;
  }
}

// ---------------- routing: logits -> top2 (no atomics; counting done later) ----------------
__global__ void moe_route(const float* __restrict__ hs,
                          const float* __restrict__ wg,
                          int* __restrict__ top_idx,
                          float* __restrict__ top_w) {
  const int token = blockIdx.x * 4 + (threadIdx.x >> 6);
  const int lane = threadIdx.x & 63;
  const float* row = hs + (size_t)token * HIDDEN;
  float acc[NEXP];
#pragma unroll
  for (int e = 0; e < NEXP; e++) acc[e] = 0.f;
  for (int j = lane; j < HIDDEN; j += 64) {
    float x = row[j];
#pragma unroll
    for (int e = 0; e < NEXP; e++) acc[e] += x * wg[e * HIDDEN + j];
  }
#pragma unroll
  for (int e = 0; e < NEXP; e++) {
    float v = acc[e];
    for (int off = 32; off > 0; off >>= 1) v += __shfl_down(v, off);
    acc[e] = v;
  }
  if (lane == 0) {
    int i0 = 0; float v0 = acc[0];
#pragma unroll
    for (int e = 1; e < NEXP; e++) if (acc[e] > v0) { v0 = acc[e]; i0 = e; }
    int i1 = -1; float v1 = -3.0e38f;
#pragma unroll
    for (int e = 0; e < NEXP; e++) if (e != i0 && acc[e] > v1) { v1 = acc[e]; i1 = e; }
    float e1 = __expf(v1 - v0);
    float s = 1.f + e1;
    top_idx[token * 2 + 0] = i0;
    top_idx[token * 2 + 1] = i1;
    top_w[token * 2 + 0] = 1.f / s;
    top_w[token * 2 + 1] = e1 / s;
  }
}

// ---------------- count: ballot-reduced histogram (256 global atomics total) ----------------
// Replaces 16384 same-line atomicAdds (G12: contended same-address atomics serialize).
__global__ void moe_count(const int* __restrict__ top_idx, int* __restrict__ counts) {
  const int tid = threadIdx.x;
  const int t = blockIdx.x * 256 + tid;
  const int lane = tid & 63;
  const int wave = tid >> 6;
  const int e0 = top_idx[t * 2 + 0];
  const int e1 = top_idx[t * 2 + 1];
  __shared__ int wcnt[8][NEXP];   // [k*4+wave][e]
#pragma unroll
  for (int e = 0; e < NEXP; e++) {
    unsigned long long m0 = __ballot(e0 == e);
    unsigned long long m1 = __ballot(e1 == e);
    if (lane == 0) {
      wcnt[wave][e] = __popcll(m0);
      wcnt[4 + wave][e] = __popcll(m1);
    }
  }
  __syncthreads();
  if (tid < NEXP) {
    int s = 0;
#pragma unroll
    for (int g = 0; g < 8; g++) s += wcnt[g][tid];
    atomicAdd(&counts[tid], s);
  }
}

__global__ void moe_scan(const int* __restrict__ counts,
                         int* __restrict__ offsets, int* __restrict__ cursor) {
  if (threadIdx.x == 0) {
    int s = 0;
    for (int e = 0; e < NEXP; e++) { offsets[e] = s; cursor[e] = s; s += counts[e]; }
  }
}

// ---------------- assign: ballot-rank + per-block base (256 global atomics) ----------------
__global__ void moe_assign2(const int* __restrict__ top_idx,
                            const float* __restrict__ top_w,
                            int* __restrict__ cursor,
                            int* __restrict__ token_of,
                            float* __restrict__ wgt_of,
                            int* __restrict__ slot_of) {
  const int tid = threadIdx.x;
  const int t = blockIdx.x * 256 + tid;
  const int lane = tid & 63;
  const int wave = tid >> 6;
  const unsigned long long below = (1ull << lane) - 1ull;
  const int e0 = top_idx[t * 2 + 0];
  const int e1 = top_idx[t * 2 + 1];
  __shared__ int wcnt[8][NEXP];    // per-group counts
  __shared__ int gbase[8][NEXP];   // intra-block group bases
  __shared__ int bbase[NEXP];      // block base within expert segment
  int rank0 = 0, rank1 = 0;
#pragma unroll
  for (int e = 0; e < NEXP; e++) {
    unsigned long long m0 = __ballot(e0 == e);
    unsigned long long m1 = __ballot(e1 == e);
    if (e0 == e) rank0 = __popcll(m0 & below);
    if (e1 == e) rank1 = __popcll(m1 & below);
    if (lane == 0) {
      wcnt[wave][e] = __popcll(m0);
      wcnt[4 + wave][e] = __popcll(m1);
    }
  }
  __syncthreads();
  if (tid < NEXP) {
    int s = 0;
#pragma unroll
    for (int g = 0; g < 8; g++) { gbase[g][tid] = s; s += wcnt[g][tid]; }
    bbase[tid] = atomicAdd(&cursor[tid], s);
  }
  __syncthreads();
  const int pos0 = bbase[e0] + gbase[wave][e0] + rank0;
  const int pos1 = bbase[e1] + gbase[4 + wave][e1] + rank1;
  token_of[pos0] = t; wgt_of[pos0] = top_w[t * 2 + 0]; slot_of[t * 2 + 0] = pos0;
  token_of[pos1] = t; wgt_of[pos1] = top_w[t * 2 + 1]; slot_of[t * 2 + 1] = pos1;
}

// LDS layout (verified, unchanged): per 16-row block (1024 B), element
//   (row, seg[16B]) at 64*row + 16*(seg ^ (row>>2)).
//
// K-loop: PHASE-SPLIT schedule (T3-style at 128x128/BK=32 scale):
//   phase A: [stage k+2 -> bufS] + ds_read late B-frags(step k) + 16 MFMA (j=0,1)
//   phase B: counted vmcnt + s_barrier  (certifies bufN = step k+1's tile)
//   phase C: ds_read early frags(step k+1) from bufN + 16 MFMA (j=2,3) + s_barrier
// Frags are register-double-buffered (ping sets P/Q, literal indices).
// lgkm waits are compiler-inserted (loads are compiler-visible). setprio(1)
// around MFMA clusters (T5; phases give waves role diversity). sched_barrier(0)
// pins region boundaries (stage can't hoist above the end barrier; reads can't
// hoist above the certify barrier). WAR safety: a buffer staged at step k was
// last ds_read at step k-1 phase A, whose reads complete before k-1's phase-C
// MFMAs (compiler wait) -> before the end-of-step barrier all waves pass.
//
// Grid: 1D, wgid&7 = expert = XCD (kept: FETCH_SIZE 476->160 MB).

// ---------------- grouped GEMM A: act = silu(hs@WgT) * (hs@WuT) ----------------
__global__ __launch_bounds__(256, 2) void gemm_gateup(
    const unsigned short* __restrict__ hs_bf,
    const unsigned short* __restrict__ wg_bf,
    const unsigned short* __restrict__ wu_bf,
    const int* __restrict__ counts,
    const int* __restrict__ offsets,
    const int* __restrict__ token_of,
    unsigned short* __restrict__ act) {
  const int wgid = blockIdx.x;
  const int e = wgid & 7;
  const int idx = wgid >> 3;
  const int ntile = idx / (TOKENS / 128);
  const int mtile = idx % (TOKENS / 128);
  const int cnt = counts[e];
  const int mbase = mtile * 128;
  if (mbase >= cnt) return;
  const int off0 = offsets[e];

  __shared__ __align__(16) unsigned short sA[3][128 * 32];
  __shared__ __align__(16) unsigned short sBg[3][128 * 32];
  __shared__ __align__(16) unsigned short sBu[3][128 * 32];
  __shared__ int rb[128];

  const int tid = threadIdx.x;
  const int wave = tid >> 6;
  const int lane = tid & 63;

  if (tid < 128) {
    int slot = off0 + mbase + tid;
    int last = off0 + cnt - 1;
    if (slot > last) slot = last;
    rb[tid] = token_of[slot] * (HIDDEN * 2);
  }
  __syncthreads();   // full drain: vmcnt==0 entering the pipelined loop

  const int srow0 = wave * 16 + (lane >> 2);
  const int srow1 = srow0 + 64;
  const int colswz = (((lane & 3) ^ (lane >> 4))) * 16;
  const char* pA = (const char*)hs_bf;
  const char* pBg = (const char*)wg_bf + (size_t)e * INTER * HIDDEN * 2;
  const char* pBu = (const char*)wu_bf + (size_t)e * INTER * HIDDEN * 2;
  const long aoff0 = (long)rb[srow0] + colswz;
  const long aoff1 = (long)rb[srow1] + colswz;
  const long boff0 = (long)(ntile * 128 + srow0) * (HIDDEN * 2) + colswz;
  const long boff1 = (long)(ntile * 128 + srow1) * (HIDDEN * 2) + colswz;

  const int lb0 = wave * 512;
  const int lb1 = 2048 + wave * 512;

  floatx4 accg[4][4], accu[4][4];
  const floatx4 zf = {0.f, 0.f, 0.f, 0.f};
#pragma unroll
  for (int i = 0; i < 4; i++)
#pragma unroll
    for (int j = 0; j < 4; j++) { accg[i][j] = zf; accu[i][j] = zf; }

  const int quad = lane >> 4;
  const int l16 = lane & 15;
  const int wm = (wave >> 1) * 64;
  const int wn = (wave & 1) * 64;
  const int ab = (wave >> 1) * 4;
  const int bb = (wave & 1) * 4;
  const int frg = l16 * 32 + (quad ^ (l16 >> 2)) * 8;

  auto stage = [&](int bi, int kk) {
    const int kb = kk * 64;  // bytes
    async16(pA + aoff0 + kb, &sA[bi][lb0]);
    async16(pA + aoff1 + kb, &sA[bi][lb1]);
    async16(pBg + boff0 + kb, &sBg[bi][lb0]);
    async16(pBg + boff1 + kb, &sBg[bi][lb1]);
    async16(pBu + boff0 + kb, &sBu[bi][lb0]);
    async16(pBu + boff1 + kb, &sBu[bi][lb1]);
  };

  bf16x8 xA[2][4], xBg[2][4], xBu[2][4];
  int ic = 0, in_ = 1, is = 2;
  const int NK = HIDDEN / 32;

  stage(0, 0);
  stage(1, 1);
  asm volatile("s_waitcnt vmcnt(6)" ::: "memory");
  __builtin_amdgcn_s_barrier();
  __builtin_amdgcn_sched_barrier(0);
#pragma unroll
  for (int i = 0; i < 4; i++) xA[0][i] = *(const bf16x8*)&sA[0][(ab + i) * 512 + frg];
  xBg[0][0] = *(const bf16x8*)&sBg[0][(bb + 0) * 512 + frg];
  xBu[0][0] = *(const bf16x8*)&sBu[0][(bb + 0) * 512 + frg];
  xBg[0][1] = *(const bf16x8*)&sBg[0][(bb + 1) * 512 + frg];
  xBu[0][1] = *(const bf16x8*)&sBu[0][(bb + 1) * 512 + frg];

#define GU_BODY(P, Q, KK, DO_STAGE, VMC)                                                            \
  {                                                                                                 \
    __builtin_amdgcn_sched_barrier(0);                                                              \
    if (DO_STAGE) stage(is, (KK) + 2);                                                              \
    xBg[P][2] = *(const bf16x8*)&sBg[ic][(bb + 2) * 512 + frg];                                     \
    xBu[P][2] = *(const bf16x8*)&sBu[ic][(bb + 2) * 512 + frg];                                     \
    xBg[P][3] = *(const bf16x8*)&sBg[ic][(bb + 3) * 512 + frg];                                     \
    xBu[P][3] = *(const bf16x8*)&sBu[ic][(bb + 3) * 512 + frg];                                     \
    __builtin_amdgcn_s_setprio(1);                                                                  \
    _Pragma("unroll")                                                                               \
    for (int i = 0; i < 4; i++) {                                                                   \
      accg[i][0] = __builtin_amdgcn_mfma_f32_16x16x32_bf16(xA[P][i], xBg[P][0], accg[i][0], 0, 0, 0); \
      accu[i][0] = __builtin_amdgcn_mfma_f32_16x16x32_bf16(xA[P][i], xBu[P][0], accu[i][0], 0, 0, 0); \
      accg[i][1] = __builtin_amdgcn_mfma_f32_16x16x32_bf16(xA[P][i], xBg[P][1], accg[i][1], 0, 0, 0); \
      accu[i][1] = __builtin_amdgcn_mfma_f32_16x16x32_bf16(xA[P][i], xBu[P][1], accu[i][1], 0, 0, 0); \
    }                                                                                               \
    __builtin_amdgcn_s_setprio(0);                                                                  \
    __builtin_amdgcn_sched_barrier(0);                                                              \
    asm volatile("s_waitcnt vmcnt(%0)" ::"n"(VMC) : "memory");                                      \
    __builtin_amdgcn_s_barrier();                                                                   \
    __builtin_amdgcn_sched_barrier(0);                                                              \
    _Pragma("unroll")                                                                               \
    for (int i = 0; i < 4; i++) xA[Q][i] = *(const bf16x8*)&sA[in_][(ab + i) * 512 + frg];          \
    xBg[Q][0] = *(const bf16x8*)&sBg[in_][(bb + 0) * 512 + frg];                                    \
    xBu[Q][0] = *(const bf16x8*)&sBu[in_][(bb + 0) * 512 + frg];                                    \
    xBg[Q][1] = *(const bf16x8*)&sBg[in_][(bb + 1) * 512 + frg];                                    \
    xBu[Q][1] = *(const bf16x8*)&sBu[in_][(bb + 1) * 512 + frg];                                    \
    __builtin_amdgcn_s_setprio(1);                                                                  \
    _Pragma("unroll")                                                                               \
    for (int i = 0; i < 4; i++) {                                                                   \
      accg[i][2] = __builtin_amdgcn_mfma_f32_16x16x32_bf16(xA[P][i], xBg[P][2], accg[i][2], 0, 0, 0); \
      accu[i][2] = __builtin_amdgcn_mfma_f32_16x16x32_bf16(xA[P][i], xBu[P][2], accu[i][2], 0, 0, 0); \
      accg[i][3] = __builtin_amdgcn_mfma_f32_16x16x32_bf16(xA[P][i], xBg[P][3], accg[i][3], 0, 0, 0); \
      accu[i][3] = __builtin_amdgcn_mfma_f32_16x16x32_bf16(xA[P][i], xBu[P][3], accu[i][3], 0, 0, 0); \
    }                                                                                               \
    __builtin_amdgcn_s_setprio(0);                                                                  \
    __builtin_amdgcn_sched_barrier(0);                                                              \
    __builtin_amdgcn_s_barrier();                                                                   \
    { int t_ = ic; ic = in_; in_ = is; is = t_; }                                                   \
  }

  for (int kk = 0; kk < NK - 2; kk += 2) {
    GU_BODY(0, 1, kk, true, 6);
    GU_BODY(1, 0, kk + 1, true, 6);
  }
  GU_BODY(0, 1, NK - 2, false, 0);
  // final step (set 1): no staging, no barriers
  xBg[1][2] = *(const bf16x8*)&sBg[ic][(bb + 2) * 512 + frg];
  xBu[1][2] = *(const bf16x8*)&sBu[ic][(bb + 2) * 512 + frg];
  xBg[1][3] = *(const bf16x8*)&sBg[ic][(bb + 3) * 512 + frg];
  xBu[1][3] = *(const bf16x8*)&sBu[ic][(bb + 3) * 512 + frg];
#pragma unroll
  for (int i = 0; i < 4; i++) {
    accg[i][0] = __builtin_amdgcn_mfma_f32_16x16x32_bf16(xA[1][i], xBg[1][0], accg[i][0], 0, 0, 0);
    accu[i][0] = __builtin_amdgcn_mfma_f32_16x16x32_bf16(xA[1][i], xBu[1][0], accu[i][0], 0, 0, 0);
    accg[i][1] = __builtin_amdgcn_mfma_f32_16x16x32_bf16(xA[1][i], xBg[1][1], accg[i][1], 0, 0, 0);
    accu[i][1] = __builtin_amdgcn_mfma_f32_16x16x32_bf16(xA[1][i], xBu[1][1], accu[i][1], 0, 0, 0);
  }
#pragma unroll
  for (int i = 0; i < 4; i++) {
    accg[i][2] = __builtin_amdgcn_mfma_f32_16x16x32_bf16(xA[1][i], xBg[1][2], accg[i][2], 0, 0, 0);
    accu[i][2] = __builtin_amdgcn_mfma_f32_16x16x32_bf16(xA[1][i], xBu[1][2], accu[i][2], 0, 0, 0);
    accg[i][3] = __builtin_amdgcn_mfma_f32_16x16x32_bf16(xA[1][i], xBg[1][3], accg[i][3], 0, 0, 0);
    accu[i][3] = __builtin_amdgcn_mfma_f32_16x16x32_bf16(xA[1][i], xBu[1][3], accu[i][3], 0, 0, 0);
  }
#undef GU_BODY

  const size_t actrow0 = (size_t)(off0 + mbase);
#pragma unroll
  for (int i = 0; i < 4; i++) {
#pragma unroll
    for (int rr = 0; rr < 4; rr++) {
      const int m = wm + i * 16 + quad * 4 + rr;
      if (mbase + m < cnt) {
        unsigned short* dst = act + (actrow0 + m) * INTER + ntile * 128 + wn + l16;
#pragma unroll
        for (int j = 0; j < 4; j++) {
          float g = accg[i][j][rr];
          float u = accu[i][j][rr];
          float s = g / (1.f + __expf(-g)) * u;
          dst[j * 16] = f2bf(s);
        }
      }
    }
  }
}

// ---------------- grouped GEMM B: slot_out[slot] = w * (act @ WdT) ----------------
__global__ __launch_bounds__(256, 3) void gemm_down(
    const unsigned short* __restrict__ act,
    const unsigned short* __restrict__ wd_bf,
    const int* __restrict__ counts,
    const int* __restrict__ offsets,
    const float* __restrict__ wgt_of,
    float* __restrict__ slot_out) {
  const int wgid = blockIdx.x;
  const int e = wgid & 7;
  const int idx = wgid >> 3;
  const int ntile = idx / (TOKENS / 128);
  const int mtile = idx % (TOKENS / 128);
  const int cnt = counts[e];
  const int mbase = mtile * 128;
  if (mbase >= cnt) return;
  const int off0 = offsets[e];

  __shared__ __align__(16) unsigned short sA[3][128 * 32];
  __shared__ __align__(16) unsigned short sB[3][128 * 32];
  __shared__ float wl[128];

  const int tid = threadIdx.x;
  const int wave = tid >> 6;
  const int lane = tid & 63;

  if (tid < 128) {
    int slot = off0 + mbase + tid;
    int last = off0 + cnt - 1;
    if (slot > last) slot = last;
    wl[tid] = wgt_of[slot];
  }
  __syncthreads();

  const int srow0 = wave * 16 + (lane >> 2);
  const int srow1 = srow0 + 64;
  const int colswz = (((lane & 3) ^ (lane >> 4))) * 16;
  const int last = off0 + cnt - 1;
  int s0 = off0 + mbase + srow0; if (s0 > last) s0 = last;
  int s1 = off0 + mbase + srow1; if (s1 > last) s1 = last;
  const char* pA = (const char*)act;
  const char* pB = (const char*)wd_bf + (size_t)e * HIDDEN * INTER * 2;
  const long aoff0 = (long)s0 * (INTER * 2) + colswz;
  const long aoff1 = (long)s1 * (INTER * 2) + colswz;
  const long boff0 = (long)(ntile * 128 + srow0) * (INTER * 2) + colswz;
  const long boff1 = (long)(ntile * 128 + srow1) * (INTER * 2) + colswz;

  const int lb0 = wave * 512;
  const int lb1 = 2048 + wave * 512;

  floatx4 acc[4][4];
  const floatx4 zf = {0.f, 0.f, 0.f, 0.f};
#pragma unroll
  for (int i = 0; i < 4; i++)
#pragma unroll
    for (int j = 0; j < 4; j++) acc[i][j] = zf;

  const int quad = lane >> 4;
  const int l16 = lane & 15;
  const int wm = (wave >> 1) * 64;
  const int wn = (wave & 1) * 64;
  const int ab = (wave >> 1) * 4;
  const int bb = (wave & 1) * 4;
  const int frg = l16 * 32 + (quad ^ (l16 >> 2)) * 8;

  auto stage = [&](int bi, int kk) {
    const int kb = kk * 64;
    async16(pA + aoff0 + kb, &sA[bi][lb0]);
    async16(pA + aoff1 + kb, &sA[bi][lb1]);
    async16(pB + boff0 + kb, &sB[bi][lb0]);
    async16(pB + boff1 + kb, &sB[bi][lb1]);
  };

  bf16x8 xa[2][4], xb[2][4];
  int ic = 0, in_ = 1, is = 2;
  const int NK = INTER / 32;

  stage(0, 0);
  stage(1, 1);
  asm volatile("s_waitcnt vmcnt(4)" ::: "memory");
  __builtin_amdgcn_s_barrier();
  __builtin_amdgcn_sched_barrier(0);
#pragma unroll
  for (int i = 0; i < 4; i++) xa[0][i] = *(const bf16x8*)&sA[0][(ab + i) * 512 + frg];
  xb[0][0] = *(const bf16x8*)&sB[0][(bb + 0) * 512 + frg];
  xb[0][1] = *(const bf16x8*)&sB[0][(bb + 1) * 512 + frg];

#define GD_BODY(P, Q, KK, DO_STAGE, VMC)                                                           \
  {                                                                                                \
    __builtin_amdgcn_sched_barrier(0);                                                             \
    if (DO_STAGE) stage(is, (KK) + 2);                                                             \
    xb[P][2] = *(const bf16x8*)&sB[ic][(bb + 2) * 512 + frg];                                      \
    xb[P][3] = *(const bf16x8*)&sB[ic][(bb + 3) * 512 + frg];                                      \
    __builtin_amdgcn_s_setprio(1);                                                                 \
    _Pragma("unroll")                                                                              \
    for (int i = 0; i < 4; i++) {                                                                  \
      acc[i][0] = __builtin_amdgcn_mfma_f32_16x16x32_bf16(xa[P][i], xb[P][0], acc[i][0], 0, 0, 0); \
      acc[i][1] = __builtin_amdgcn_mfma_f32_16x16x32_bf16(xa[P][i], xb[P][1], acc[i][1], 0, 0, 0); \
    }                                                                                              \
    __builtin_amdgcn_s_setprio(0);                                                                 \
    __builtin_amdgcn_sched_barrier(0);                                                             \
    asm volatile("s_waitcnt vmcnt(%0)" ::"n"(VMC) : "memory");                                     \
    __builtin_amdgcn_s_barrier();                                                                  \
    __builtin_amdgcn_sched_barrier(0);                                                             \
    _Pragma("unroll")                                                                              \
    for (int i = 0; i < 4; i++) xa[Q][i] = *(const bf16x8*)&sA[in_][(ab + i) * 512 + frg];         \
    xb[Q][0] = *(const bf16x8*)&sB[in_][(bb + 0) * 512 + frg];                                     \
    xb[Q][1] = *(const bf16x8*)&sB[in_][(bb + 1) * 512 + frg];                                     \
    __builtin_amdgcn_s_setprio(1);                                                                 \
    _Pragma("unroll")                                                                              \
    for (int i = 0; i < 4; i++) {                                                                  \
      acc[i][2] = __builtin_amdgcn_mfma_f32_16x16x32_bf16(xa[P][i], xb[P][2], acc[i][2], 0, 0, 0); \
      acc[i][3] = __builtin_amdgcn_mfma_f32_16x16x32_bf16(xa[P][i], xb[P][3], acc[i][3], 0, 0, 0); \
    }                                                                                              \
    __builtin_amdgcn_s_setprio(0);                                                                 \
    __builtin_amdgcn_sched_barrier(0);                                                             \
    __builtin_amdgcn_s_barrier();                                                                  \
    { int t_ = ic; ic = in_; in_ = is; is = t_; }                                                  \
  }

  for (int kk = 0; kk < NK - 2; kk += 2) {
    GD_BODY(0, 1, kk, true, 4);
    GD_BODY(1, 0, kk + 1, true, 4);
  }
  GD_BODY(0, 1, NK - 2, false, 0);
  // final step (set 1)
  xb[1][2] = *(const bf16x8*)&sB[ic][(bb + 2) * 512 + frg];
  xb[1][3] = *(const bf16x8*)&sB[ic][(bb + 3) * 512 + frg];
#pragma unroll
  for (int i = 0; i < 4; i++) {
    acc[i][0] = __builtin_amdgcn_mfma_f32_16x16x32_bf16(xa[1][i], xb[1][0], acc[i][0], 0, 0, 0);
    acc[i][1] = __builtin_amdgcn_mfma_f32_16x16x32_bf16(xa[1][i], xb[1][1], acc[i][1], 0, 0, 0);
  }
#pragma unroll
  for (int i = 0; i < 4; i++) {
    acc[i][2] = __builtin_amdgcn_mfma_f32_16x16x32_bf16(xa[1][i], xb[1][2], acc[i][2], 0, 0, 0);
    acc[i][3] = __builtin_amdgcn_mfma_f32_16x16x32_bf16(xa[1][i], xb[1][3], acc[i][3], 0, 0, 0);
  }
#undef GD_BODY

#pragma unroll
  for (int i = 0; i < 4; i++) {
#pragma unroll
    for (int rr = 0; rr < 4; rr++) {
      const int m = wm + i * 16 + quad * 4 + rr;
      if (mbase + m < cnt) {
        const float w = wl[m];
        float* dst = slot_out + (size_t)(off0 + mbase + m) * HIDDEN + ntile * 128 + wn + l16;
#pragma unroll
        for (int j = 0; j < 4; j++) dst[j * 16] = acc[i][j][rr] * w;
      }
    }
  }
}

// ---------------- combine: out[t] = slot_out[slotA] + slot_out[slotB] ----------------
__global__ void moe_combine(const float* __restrict__ slot_out,
                            const int* __restrict__ slot_of,
                            float* __restrict__ out) {
  const int idx = blockIdx.x * 256 + threadIdx.x;
  const int t = idx >> 8;
  const int c4 = idx & 255;
  const int sa = slot_of[t * 2 + 0];
  const int sb = slot_of[t * 2 + 1];
  float4 a = ((const float4*)(slot_out + (size_t)sa * HIDDEN))[c4];
  float4 b = ((const float4*)(slot_out + (size_t)sb * HIDDEN))[c4];
  float4 o;
  o.x = a.x + b.x; o.y = a.y + b.y; o.z = a.z + b.z; o.w = a.w + b.w;
  ((float4*)(out + (size_t)t * HIDDEN))[c4] = o;
}

extern "C" void kernel_launch(void* const* d_in, const int* in_sizes, int n_in,
                              void* d_out, int out_size, void* d_ws, size_t ws_size,
                              hipStream_t stream) {
  const float* hs = (const float*)d_in[0];
  const float* wg = (const float*)d_in[1];
  const float* wgp = (const float*)d_in[2];
  const float* wup = (const float*)d_in[3];
  const float* wdp = (const float*)d_in[4];
  float* out = (float*)d_out;

  char* ws = (char*)d_ws;
  int* counts = (int*)(ws + 0);
  int* cursor = (int*)(ws + 256);
  int* offsets = (int*)(ws + 512);
  int* top_idx = (int*)(ws + 1024);
  float* top_w = (float*)(ws + 1024 + 65536);
  int* token_of = (int*)(ws + 1024 + 2 * 65536);
  float* wgt_of = (float*)(ws + 1024 + 3 * 65536);
  int* slot_of = (int*)(ws + 1024 + 4 * 65536);
  size_t base = 1024 + 5 * 65536;
  unsigned short* hs_bf = (unsigned short*)(ws + base);
  base += (size_t)TOKENS * HIDDEN * 2;
  unsigned short* wg_bf = (unsigned short*)(ws + base);
  base += (size_t)NEXP * INTER * HIDDEN * 2;
  unsigned short* wu_bf = (unsigned short*)(ws + base);
  base += (size_t)NEXP * INTER * HIDDEN * 2;
  unsigned short* wd_bf = (unsigned short*)(ws + base);
  base += (size_t)NEXP * HIDDEN * INTER * 2;
  unsigned short* act = (unsigned short*)(ws + base);
  // slot_out aliases wg_bf/wu_bf (dead after gemm_gateup): 67.1 MB <= 92.3 MB
  float* slot_out = (float*)wg_bf;

  hipMemsetAsync(d_ws, 0, 768, stream);

  cvt_bf16_4<<<dim3(2048, 1, 4), 256, 0, stream>>>(
      hs, hs_bf, TOKENS * HIDDEN / 4,
      wgp, wg_bf, NEXP * INTER * HIDDEN / 4,
      wup, wu_bf, NEXP * INTER * HIDDEN / 4,
      wdp, wd_bf, NEXP * HIDDEN * INTER / 4);

  moe_route<<<TOKENS / 4, 256, 0, stream>>>(hs, wg, top_idx, top_w);
  moe_count<<<TOKENS / 256, 256, 0, stream>>>(top_idx, counts);
  moe_scan<<<1, 64, 0, stream>>>(counts, offsets, cursor);
  moe_assign2<<<TOKENS / 256, 256, 0, stream>>>(top_idx, top_w, cursor, token_of, wgt_of, slot_of);

  gemm_gateup<<<dim3((INTER / 128) * (TOKENS / 128) * NEXP), 256, 0, stream>>>(
      hs_bf, wg_bf, wu_bf, counts, offsets, token_of, act);
  gemm_down<<<dim3((HIDDEN / 128) * (TOKENS / 128) * NEXP), 256, 0, stream>>>(
      act, wd_bf, counts, offsets, wgt_of, slot_out);
  moe_combine<<<TOKENS, 256, 0, stream>>>(slot_out, slot_of, out);
}